// Round 7
// baseline (558.836 us; speedup 1.0000x reference)
//
#include <hip/hip_runtime.h>
#include <stdint.h>

// Problem constants (B,H,W,C)=(2,192,192,192), WS=16, SHIFT=8, NH=6
#define HH 192
#define WWW 192
#define CC 192
#define WS 16
#define SHIFTS 8
#define NH 6
#define HD 32
#define NN 256
#define NWS 12
#define NWIN_B 144
#define NWIN 288
#define CTN (NWIN * NN)          // 73728 floats per ct table

typedef _Float16 half_t;
typedef half_t half2_t __attribute__((ext_vector_type(2)));
typedef half_t f16x8 __attribute__((ext_vector_type(8)));   // MFMA A/B frag (4 VGPR)
typedef float f32x4 __attribute__((ext_vector_type(4)));    // MFMA C/D frag
typedef uint32_t u32x4 __attribute__((ext_vector_type(4)));

#define LOG2E 1.4426950408889634f

#if __has_builtin(__builtin_amdgcn_exp2f)
#define EXP2F(x) __builtin_amdgcn_exp2f(x)
#else
#define EXP2F(x) __expf(0.6931471805599453f * (x))
#endif

// saturating f32->f16 pack: launders NaN (fminf/fmaxf drop NaN operand) and caps inf
__device__ __forceinline__ float sat16(float a) {
    return fminf(fmaxf(a, -60000.f), 60000.f);
}
__device__ __forceinline__ uint32_t pack_h2(float a, float b) {
    half2_t h; h.x = (half_t)sat16(a); h.y = (half_t)sat16(b);
    return __builtin_bit_cast(uint32_t, h);
}
// p is already bounded in [0, 2^15] (exp2 of clamped arg): plain rte casts
__device__ __forceinline__ uint32_t pack_p(float a, float b) {
    half2_t h; h.x = (half_t)a; h.y = (half_t)b;
    return __builtin_bit_cast(uint32_t, h);
}

// post-shift (sh,sw) -> original coords (roll by -SHIFT: s[i] = x[(i+SHIFT)%N])
__device__ __forceinline__ size_t xrow(int b, int sh, int sw) {
    int oh = sh + SHIFTS; if (oh >= HH) oh -= HH;
    int ow = sw + SHIFTS; if (ow >= WWW) ow -= WWW;
    return ((size_t)((b * HH + oh) * WWW + ow)) * CC;
}
__device__ __forceinline__ size_t qkvrow(int b, int sh, int sw) {
    int oh = sh + SHIFTS; if (oh >= HH) oh -= HH;
    int ow = sw + SHIFTS; if (ow >= WWW) ow -= WWW;
    return ((size_t)((b * HH + oh) * WWW + ow)) * (3 * CC);
}
// shift-mask region id along one axis (post-shift / mask-image coordinates)
__device__ __forceinline__ int regof(int v) { return v < (HH - WS) ? 0 : (v < (HH - SHIFTS) ? 1 : 2); }

// ct tables parked in SECOND halves (floats [96,192)) of d_out row-slots 0..3071.
// flat index q in [0, 2*CTN) -> float position in d_out.
__device__ __forceinline__ float* ctptr(float* o, int q) {
    int slot = q / 96;            // magic-mul, constant divisor
    int off = q - slot * 96;
    return o + (size_t)slot * CC + 96 + off;
}

// ---------------- Kernel A: geo cumsum tables (once per window) ----------------
// 512 threads: channel range split across two 256-thread halves (2x waves/CU vs 256).
__global__ __launch_bounds__(512) void kgeo(const float* __restrict__ x,
                                            const float* __restrict__ sigp,
                                            float* __restrict__ outbuf) {
    __shared__ float dh[2][16][16];
    __shared__ float dv[2][16][16];
    int win = blockIdx.x;
    int b = win / NWIN_B, wi = win % NWIN_B;
    int wr = wi / NWS, wc = wi % NWS;
    int t = threadIdx.x;
    int hf = t >> 8, tt = t & 255;
    int r = tt >> 4, j = tt & 15;
    int r1 = (r < 15) ? r + 1 : r;
    int j1 = (j < 15) ? j + 1 : j;

    const float4* a4 = (const float4*)(x + xrow(b, wr * WS + r,  wc * WS + j))  + hf * 24;
    const float4* b4 = (const float4*)(x + xrow(b, wr * WS + r,  wc * WS + j1)) + hf * 24;
    const float4* c4 = (const float4*)(x + xrow(b, wr * WS + r1, wc * WS + j))  + hf * 24;
    float sh_ = 0.f, sv_ = 0.f;
    #pragma unroll 4
    for (int ch = 0; ch < 24; ch++) {
        float4 fa = a4[ch], fb = b4[ch], fc = c4[ch];
        sh_ += fabsf(fb.x - fa.x) + fabsf(fb.y - fa.y) + fabsf(fb.z - fa.z) + fabsf(fb.w - fa.w);
        sv_ += fabsf(fc.x - fa.x) + fabsf(fc.y - fa.y) + fabsf(fc.z - fa.z) + fabsf(fc.w - fa.w);
    }
    dh[hf][r][j] = (j < 15) ? sh_ : 0.f;
    dv[hf][r][j] = (r < 15) ? sv_ : 0.f;
    __syncthreads();

    float sigma = fabsf(sigp[0]);
    if (t < 16) {
        float acc = 0.f;
        *ctptr(outbuf, win * NN + t * 16) = 0.f;
        for (int jj = 1; jj < 16; jj++) {
            acc += 1.0f + sigma * (dh[0][t][jj - 1] + dh[1][t][jj - 1]);
            *ctptr(outbuf, win * NN + t * 16 + jj) = acc;
        }
    } else if (t < 32) {
        int c = t - 16;
        float acc = 0.f;
        *ctptr(outbuf, CTN + win * NN + c) = 0.f;
        for (int ii = 1; ii < 16; ii++) {
            acc += 1.0f + sigma * (dv[0][ii - 1][c] + dv[1][ii - 1][c]);
            *ctptr(outbuf, CTN + win * NN + ii * 16 + c) = acc;
        }
    }
}

// ------- Kernel B: MFMA windowed attention; f16 att -> first half of own d_out row-slot -------
// 8 waves/block (512 thr); wave w owns q-rows [32w, 32w+32) = window rows 2w, 2w+1.
// SWAPPED QK^T: S^T = mfma(A=K, B=Q); lane owns P[q=dl][k=g*4+r]; PV A-frag via shfl.
// Mask-free fast path for interior windows (wr<11 && wc<11): shift mask identically 0.
// launch_bounds (512,6): VGPR cap 85; body compiles ~60 natural (r5/r6) so no spill.
// LDS 44.3KB -> 3 blocks/CU, 24 waves/CU (6/SIMD) -- the occupancy lever this round.
// (r6's 31.7KB rpbT b128 table was issue-neutral but blocked 3 blocks/CU: reverted.)
__global__ __launch_bounds__(512, 6) void kattn(const float* __restrict__ qkv,
                                                const float* __restrict__ rpb_table,
                                                const float* __restrict__ geo_scale,
                                                float* __restrict__ outbuf) {
    __shared__ __align__(16) uint32_t Klds[256 * 20];     // [token][40 halves], 80B pitch (reused for O)
    __shared__ __align__(16) uint32_t Vt[32 * 140];       // [d][280 halves], 560B pitch (transposed V)
    __shared__ __align__(16) float cth_s[NN];
    __shared__ __align__(16) float ctv_s[NN];
    __shared__ float rpb_s[961];

    int win = blockIdx.x, head = blockIdx.y;
    int b = win / NWIN_B, wi = win % NWIN_B;
    int wr = wi / NWS, wc = wi % NWS;
    int wr16 = wr * WS, wc16 = wc * WS;
    int t = threadIdx.x;
    int dl = t & 15;          // lane&15: A-row / B-col / D-col index
    int g = (t >> 4) & 3;     // lane>>4 within wave: k-chunk / D-row-group
    int g4 = g * 4;
    int w = t >> 6;           // wave id 0..7

    // pre-scaled rpb (fold log2(e) into all additive bias terms)
    for (int i = t; i < 961; i += 512) rpb_s[i] = rpb_table[i * NH + head] * LOG2E;

    // stage K row t -> Klds[t][0..31] (f16, channel order)   [waves 0..3]
    if (t < 256) {
        int r = t >> 4, c = t & 15;
        const float4* k4 = (const float4*)(qkv + qkvrow(b, wr16 + r, wc16 + c) + CC + head * HD);
        uint32_t kp[16];
        #pragma unroll
        for (int c4 = 0; c4 < 8; c4++) {
            float4 u = k4[c4];
            kp[c4 * 2 + 0] = pack_h2(u.x, u.y);
            kp[c4 * 2 + 1] = pack_h2(u.z, u.w);
        }
        uint4* dst = (uint4*)((char*)Klds + t * 80);
        #pragma unroll
        for (int i = 0; i < 4; i++)
            dst[i] = make_uint4(kp[i * 4 + 0], kp[i * 4 + 1], kp[i * 4 + 2], kp[i * 4 + 3]);
    } else if (t < 384) {
        // stage V transposed: Vt[d][k] halves; token pair (2tv, 2tv+1)   [waves 4..5]
        int tv = t - 256;
        int p0 = 2 * tv, p1 = 2 * tv + 1;
        const float4* v0 = (const float4*)(qkv + qkvrow(b, wr16 + (p0 >> 4), wc16 + (p0 & 15)) + 2 * CC + head * HD);
        const float4* v1 = (const float4*)(qkv + qkvrow(b, wr16 + (p1 >> 4), wc16 + (p1 & 15)) + 2 * CC + head * HD);
        #pragma unroll
        for (int c4 = 0; c4 < 8; c4++) {
            float4 a = v0[c4], bu = v1[c4];
            Vt[(c4 * 4 + 0) * 140 + tv] = pack_h2(a.x, bu.x);
            Vt[(c4 * 4 + 1) * 140 + tv] = pack_h2(a.y, bu.y);
            Vt[(c4 * 4 + 2) * 140 + tv] = pack_h2(a.z, bu.z);
            Vt[(c4 * 4 + 3) * 140 + tv] = pack_h2(a.w, bu.w);
        }
    } else {
        // stage ct tables   [waves 6..7]
        int tc = t - 384;   // 0..127
        cth_s[tc]       = *ctptr(outbuf, win * NN + tc);
        cth_s[tc + 128] = *ctptr(outbuf, win * NN + tc + 128);
        ctv_s[tc]       = *ctptr(outbuf, CTN + win * NN + tc);
        ctv_s[tc + 128] = *ctptr(outbuf, CTN + win * NN + tc + 128);
    }
    // Q B-fragments: qt -> window row 2w+qt, col dl; k-dim channels g*8..g*8+7
    f16x8 qf[2];
    #pragma unroll
    for (int qt = 0; qt < 2; qt++) {
        const float* qp = qkv + qkvrow(b, wr16 + 2 * w + qt, wc16 + dl) + head * HD + g * 8;
        float4 u0 = ((const float4*)qp)[0];
        float4 u1 = ((const float4*)qp)[1];
        f16x8 q8;
        q8[0] = (half_t)sat16(u0.x); q8[1] = (half_t)sat16(u0.y);
        q8[2] = (half_t)sat16(u0.z); q8[3] = (half_t)sat16(u0.w);
        q8[4] = (half_t)sat16(u1.x); q8[5] = (half_t)sat16(u1.y);
        q8[6] = (half_t)sat16(u1.z); q8[7] = (half_t)sat16(u1.w);
        qf[qt] = q8;
    }
    __syncthreads();

    // per-lane static bias tables. Element ownership after swap:
    //   lane (g,dl) of tile (qt,kt) holds S[q=(2w+qt)*16+dl][k=kv0+kt*16+g*4+r]
    float gscale2 = geo_scale[head] * LOG2E;
    float ghs[2][4];   // -gscale2*|cth[rq16+ck] - cth[q]|  (static per qt,r)
    f32x4 Dv[2];       // ctv[rq16 + g4 + r]                (static per qt,r)
    int regq[2], qb0[2];
    #pragma unroll
    for (int qt = 0; qt < 2; qt++) {
        int rq = 2 * w + qt;
        float chq = cth_s[rq * 16 + dl];
        f32x4 Bv = *(const f32x4*)&cth_s[rq * 16 + g4];
        Dv[qt] = *(const f32x4*)&ctv_s[rq * 16 + g4];
        #pragma unroll
        for (int r = 0; r < 4; r++) ghs[qt][r] = -gscale2 * fabsf(Bv[r] - chq);
        regq[qt] = 3 * regof(wr16 + rq) + regof(wc16 + dl);
        qb0[qt] = rq * 31 + dl + 480 - g4;
    }
    int regkc[4];
    #pragma unroll
    for (int r = 0; r < 4; r++) regkc[r] = regof(wc16 + g4 + r);
    const float scale2 = 0.17677669529663687f * LOG2E;   // 32^-0.5 * log2(e)

    f32x4 o[2][2];
    #pragma unroll
    for (int qt = 0; qt < 2; qt++) { o[qt][0] = (f32x4){0.f,0.f,0.f,0.f}; o[qt][1] = (f32x4){0.f,0.f,0.f,0.f}; }
    float lq[2] = {0.f, 0.f};

    const char* KB = (const char*)Klds;
    const char* VB = (const char*)Vt;
    const f32x4 zf = {0.f, 0.f, 0.f, 0.f};
    int srcA = ((g & 1) << 5) + dl;   // shfl source lanes for PV A-frag assembly
    int srcB = srcA + 16;
    bool hi = (g >= 2);

#define KVLOOP(MASKED)                                                                  \
    _Pragma("unroll 2")                                                                 \
    for (int kvb = 0; kvb < 8; kvb++) {                                                 \
        int kv0 = kvb * 32;                                                             \
        f16x8 ak0 = *(const f16x8*)(KB + (size_t)(kv0 + dl) * 80 + g * 16);             \
        f16x8 ak1 = *(const f16x8*)(KB + (size_t)(kv0 + 16 + dl) * 80 + g * 16);        \
        f32x4 s[2][2];                                                                  \
        s[0][0] = __builtin_amdgcn_mfma_f32_16x16x32_f16(ak0, qf[0], zf, 0, 0, 0);      \
        s[0][1] = __builtin_amdgcn_mfma_f32_16x16x32_f16(ak1, qf[0], zf, 0, 0, 0);      \
        s[1][0] = __builtin_amdgcn_mfma_f32_16x16x32_f16(ak0, qf[1], zf, 0, 0, 0);      \
        s[1][1] = __builtin_amdgcn_mfma_f32_16x16x32_f16(ak1, qf[1], zf, 0, 0, 0);      \
        f32x4 cv0 = *(const f32x4*)&ctv_s[kv0 + g4];                                    \
        f32x4 cv1 = *(const f32x4*)&ctv_s[kv0 + 16 + g4];                               \
        uint32_t pkk[2][2][2];                                                          \
        _Pragma("unroll")                                                               \
        for (int qt = 0; qt < 2; qt++) {                                                \
            _Pragma("unroll")                                                           \
            for (int kt = 0; kt < 2; kt++) {                                            \
                int rk = kvb * 2 + kt;                                                  \
                int rowreg = MASKED ? 3 * regof(wr16 + rk) : 0;                         \
                int idxk = qb0[qt] - rk * 31;                                           \
                float pr[4];                                                            \
                _Pragma("unroll")                                                       \
                for (int r = 0; r < 4; r++) {                                           \
                    float C = kt ? cv1[r] : cv0[r];                                     \
                    float geoV = fabsf(C - Dv[qt][r]);                                  \
                    float bias = rpb_s[idxk - r] + ghs[qt][r];                          \
                    if (MASKED)                                                         \
                        bias += ((rowreg + regkc[r] == regq[qt]) ? 0.f : -100.f * LOG2E); \
                    float tt2 = fmaf(s[qt][kt][r], scale2, fmaf(-gscale2, geoV, bias)); \
                    tt2 = fminf(fmaxf(tt2, -1000.f), 15.f);                             \
                    float p = EXP2F(tt2);                                               \
                    lq[qt] += p;                                                        \
                    pr[r] = p;                                                          \
                }                                                                       \
                pkk[qt][kt][0] = pack_p(pr[0], pr[1]);                                  \
                pkk[qt][kt][1] = pack_p(pr[2], pr[3]);                                  \
            }                                                                           \
        }                                                                               \
        f16x8 bv0 = *(const f16x8*)(VB + (size_t)dl * 560 + kv0 * 2 + g * 16);          \
        f16x8 bv1 = *(const f16x8*)(VB + (size_t)(16 + dl) * 560 + kv0 * 2 + g * 16);   \
        _Pragma("unroll")                                                               \
        for (int qt = 0; qt < 2; qt++) {                                                \
            uint32_t a00 = __shfl((int)pkk[qt][0][0], srcA), a01 = __shfl((int)pkk[qt][0][1], srcA); \
            uint32_t a10 = __shfl((int)pkk[qt][0][0], srcB), a11 = __shfl((int)pkk[qt][0][1], srcB); \
            uint32_t b00 = __shfl((int)pkk[qt][1][0], srcA), b01 = __shfl((int)pkk[qt][1][1], srcA); \
            uint32_t b10 = __shfl((int)pkk[qt][1][0], srcB), b11 = __shfl((int)pkk[qt][1][1], srcB); \
            u32x4 uu;                                                                   \
            uu.x = hi ? b00 : a00; uu.y = hi ? b01 : a01;                               \
            uu.z = hi ? b10 : a10; uu.w = hi ? b11 : a11;                               \
            f16x8 ap = __builtin_bit_cast(f16x8, uu);                                   \
            o[qt][0] = __builtin_amdgcn_mfma_f32_16x16x32_f16(ap, bv0, o[qt][0], 0, 0, 0); \
            o[qt][1] = __builtin_amdgcn_mfma_f32_16x16x32_f16(ap, bv1, o[qt][1], 0, 0, 0); \
        }                                                                               \
    }

    if (wr < 11 && wc < 11) {
        // interior window: all region ids 0 -> shift mask identically zero
        KVLOOP(false)
    } else {
        KVLOOP(true)
    }
#undef KVLOOP

    // row sums: lane holds partial sum for q=dl of each qt tile; reduce over the
    // 4 g-groups (lanes ^16, ^32), then fetch inv for the o-rows this lane owns.
    float invr[2][4];
    #pragma unroll
    for (int qt = 0; qt < 2; qt++) {
        float li = lq[qt];
        li += __shfl_xor(li, 16);
        li += __shfl_xor(li, 32);
        float iv = 1.0f / li;
        #pragma unroll
        for (int r = 0; r < 4; r++) invr[qt][r] = __shfl(iv, g4 + r);
    }

    // all waves done reading K -> reuse Klds as per-wave O transpose buffer
    __syncthreads();
    char* OB = (char*)Klds + w * 2560;   // [32 rows][80B]
    #pragma unroll
    for (int qt = 0; qt < 2; qt++)
        #pragma unroll
        for (int dt = 0; dt < 2; dt++)
            #pragma unroll
            for (int r = 0; r < 4; r++) {
                float val = o[qt][dt][r] * invr[qt][r];
                *(half_t*)(OB + (qt * 16 + g4 + r) * 80 + (dt * 16 + dl) * 2) = (half_t)sat16(val);
            }

    // wave w stores its own 32 tokens; lane pair (lp, half) -> 32B each (no barrier needed)
    int lane = t & 63;
    int lp = lane >> 1, half = lane & 1;
    int tok = 32 * w + lp;
    int rr = tok >> 4, pc = tok & 15;
    int oh = wr16 + rr + SHIFTS; if (oh >= HH) oh -= HH;
    int ow = wc16 + pc + SHIFTS; if (ow >= WWW) ow -= WWW;
    size_t R = (size_t)b * (HH * WWW) + (size_t)oh * WWW + ow;
    uint4* o4p = (uint4*)outbuf;
    const uint4* src = (const uint4*)(OB + lp * 80 + half * 32);
    size_t base4 = R * 48 + head * 4 + half * 2;
    o4p[base4 + 0] = src[0];
    o4p[base4 + 1] = src[1];
}

// ------- Kernel C: MFMA projection GEMM on d_out (f16 A in slot-half, f32 out full slot) -------
// 512 threads = 8 waves; wave w owns rows [R0+16w, R0+16w+16) -> reads its own rows' f16
// halves (A-frags direct from global, L3-resident) and stores f32 to the same rows:
// stores depend on acc -> all A loads retired first; cross-wave rows disjoint -> race-free.
// W staged once per block as f16 in LDS (400B pitch -> 2-way-free b128 B-frags).
__global__ __launch_bounds__(512, 4) void kproj(float* __restrict__ data,
                                                const float* __restrict__ proj_w,
                                                const float* __restrict__ proj_b) {
    __shared__ __align__(16) uint32_t Wh[192 * 100];   // f16 W[j][c], pitch 400B (192 ch + pad)
    int t = threadIdx.x;
    size_t R0 = (size_t)blockIdx.x * 128;

    // stage W -> f16 LDS: W[j][c] row-major, halves contiguous in c
    const float4* pw4 = (const float4*)proj_w;
    for (int q = t; q < 9216; q += 512) {
        int j = q / 48, c4 = q - j * 48;
        float4 u = pw4[q];
        *(uint2*)&Wh[j * 100 + c4 * 2] = make_uint2(pack_h2(u.x, u.y), pack_h2(u.z, u.w));
    }
    __syncthreads();

    int dl = t & 15, g = (t >> 4) & 3, w = t >> 6;
    const char* WB = (const char*)Wh;
    const char* AB = (const char*)data;

    f32x4 acc[12];
    #pragma unroll
    for (int i = 0; i < 12; i++) acc[i] = (f32x4){0.f, 0.f, 0.f, 0.f};

    // A-frag: row = dl (global row R0+16w+dl), k = c = ch*32 + g*8 + j  (16B load per chunk)
    size_t arow = (size_t)(R0 + w * 16 + dl) * 768;
    #pragma unroll
    for (int ch = 0; ch < 6; ch++) {
        f16x8 af = *(const f16x8*)(AB + arow + ch * 64 + g * 16);
        #pragma unroll
        for (int jt = 0; jt < 12; jt++) {
            // B-frag: col = j = jt*16+dl, k = c  (Wh[j][c] contiguous halves)
            f16x8 bf = *(const f16x8*)(WB + (size_t)(jt * 16 + dl) * 400 + ch * 64 + g * 16);
            acc[jt] = __builtin_amdgcn_mfma_f32_16x16x32_f16(af, bf, acc[jt], 0, 0, 0);
        }
    }

    // bias + f32 stores: D row = g*4+r (own wave's rows), col = jt*16+dl
    float bvv[12];
    #pragma unroll
    for (int jt = 0; jt < 12; jt++) bvv[jt] = proj_b[jt * 16 + dl];
    size_t orow = (size_t)(R0 + w * 16 + g * 4) * 192;
    #pragma unroll
    for (int jt = 0; jt < 12; jt++)
        #pragma unroll
        for (int r = 0; r < 4; r++)
            data[orow + (size_t)r * 192 + jt * 16 + dl] = acc[jt][r] + bvv[jt];
}

extern "C" void kernel_launch(void* const* d_in, const int* in_sizes, int n_in,
                              void* d_out, int out_size, void* d_ws, size_t ws_size,
                              hipStream_t stream) {
    // Resolve float32 inputs by unique element count (belt-and-braces vs dict order)
    const float *x = nullptr, *qkv = nullptr, *rpb = nullptr, *gsc = nullptr,
                *pw = nullptr, *pb = nullptr, *sig = nullptr;
    for (int i = 0; i < n_in; i++) {
        switch (in_sizes[i]) {
            case 14155776: x   = (const float*)d_in[i]; break;  // 2*192*192*192
            case 42467328: qkv = (const float*)d_in[i]; break;  // 3x
            case 5766:     rpb = (const float*)d_in[i]; break;  // 961*6
            case 6:        gsc = (const float*)d_in[i]; break;  // NH
            case 36864:    pw  = (const float*)d_in[i]; break;  // 192*192
            case 192:      pb  = (const float*)d_in[i]; break;
            default: break;  // rpi(65536), attn_mask(589824), scalars
        }
    }
    // geo_sigma: first size-1 input in dict order (index 4 per setup_inputs)
    if (n_in > 4 && in_sizes[4] == 1) sig = (const float*)d_in[4];
    else for (int i = 0; i < n_in; i++) if (in_sizes[i] == 1) { sig = (const float*)d_in[i]; break; }
    // fallback to dict order if anything unresolved
    if (!x)   x   = (const float*)d_in[0];
    if (!qkv) qkv = (const float*)d_in[1];
    if (!rpb) rpb = (const float*)d_in[2];
    if (!gsc) gsc = (const float*)d_in[3];
    if (!sig) sig = (const float*)d_in[4];
    if (!pw)  pw  = (const float*)d_in[5];
    if (!pb)  pb  = (const float*)d_in[6];

    float* out = (float*)d_out;   // reference output dtype: float32
    // d_ws unused: ct tables live in second halves of d_out row-slots 0..3071;
    // f16 att lives in the first half of each row's own f32 slot (in-place kproj).

    kgeo<<<dim3(NWIN), dim3(512), 0, stream>>>(x, sig, out);
    kattn<<<dim3(NWIN, NH), dim3(512), 0, stream>>>(qkv, rpb, gsc, out);
    kproj<<<dim3((NWIN * NN) / 128), dim3(512), 0, stream>>>(out, pw, pb);
}

// Round 8
// 395.785 us; speedup vs baseline: 1.4120x; 1.4120x over previous
//
#include <hip/hip_runtime.h>
#include <stdint.h>

// Problem constants (B,H,W,C)=(2,192,192,192), WS=16, SHIFT=8, NH=6
#define HH 192
#define WWW 192
#define CC 192
#define WS 16
#define SHIFTS 8
#define NH 6
#define HD 32
#define NN 256
#define NWS 12
#define NWIN_B 144
#define NWIN 288
#define CTN (NWIN * NN)          // 73728 floats per ct table

typedef _Float16 half_t;
typedef half_t half2_t __attribute__((ext_vector_type(2)));
typedef half_t f16x8 __attribute__((ext_vector_type(8)));   // MFMA A/B frag (4 VGPR)
typedef float f32x4 __attribute__((ext_vector_type(4)));    // MFMA C/D frag
typedef uint32_t u32x4 __attribute__((ext_vector_type(4)));

#define LOG2E 1.4426950408889634f

#if __has_builtin(__builtin_amdgcn_exp2f)
#define EXP2F(x) __builtin_amdgcn_exp2f(x)
#else
#define EXP2F(x) __expf(0.6931471805599453f * (x))
#endif

// saturating f32->f16 pack: launders NaN (fminf/fmaxf drop NaN operand) and caps inf
__device__ __forceinline__ float sat16(float a) {
    return fminf(fmaxf(a, -60000.f), 60000.f);
}
__device__ __forceinline__ uint32_t pack_h2(float a, float b) {
    half2_t h; h.x = (half_t)sat16(a); h.y = (half_t)sat16(b);
    return __builtin_bit_cast(uint32_t, h);
}
// p is already bounded in [0, 2^15] (exp2 of clamped arg): plain rte casts
__device__ __forceinline__ uint32_t pack_p(float a, float b) {
    half2_t h; h.x = (half_t)a; h.y = (half_t)b;
    return __builtin_bit_cast(uint32_t, h);
}

// post-shift (sh,sw) -> original coords (roll by -SHIFT: s[i] = x[(i+SHIFT)%N])
__device__ __forceinline__ size_t xrow(int b, int sh, int sw) {
    int oh = sh + SHIFTS; if (oh >= HH) oh -= HH;
    int ow = sw + SHIFTS; if (ow >= WWW) ow -= WWW;
    return ((size_t)((b * HH + oh) * WWW + ow)) * CC;
}
__device__ __forceinline__ size_t qkvrow(int b, int sh, int sw) {
    int oh = sh + SHIFTS; if (oh >= HH) oh -= HH;
    int ow = sw + SHIFTS; if (ow >= WWW) ow -= WWW;
    return ((size_t)((b * HH + oh) * WWW + ow)) * (3 * CC);
}
// shift-mask region id along one axis (post-shift / mask-image coordinates)
__device__ __forceinline__ int regof(int v) { return v < (HH - WS) ? 0 : (v < (HH - SHIFTS) ? 1 : 2); }

// ct tables parked in SECOND halves (floats [96,192)) of d_out row-slots 0..3071.
// flat index q in [0, 2*CTN) -> float position in d_out.
__device__ __forceinline__ float* ctptr(float* o, int q) {
    int slot = q / 96;            // magic-mul, constant divisor
    int off = q - slot * 96;
    return o + (size_t)slot * CC + 96 + off;
}

// ---------------- Kernel A: geo cumsum tables (once per window) ----------------
// 512 threads. Window x staged into LDS TRANSPOSED xs[ch][token] in two 96-channel
// chunks: global bytes read exactly once (56.6MB total vs 170MB logical in the
// unstaged version), fully coalesced (384B contiguous per token per chunk).
// Neighbor-diff reads then hit LDS at consecutive-token addresses (conflict-free);
// staging writes are 2-lane aliased (free on 32-bank wave64).
__global__ __launch_bounds__(512) void kgeo(const float* __restrict__ x,
                                            const float* __restrict__ sigp,
                                            float* __restrict__ outbuf) {
    __shared__ float xs[96][256];     // [channel-in-chunk][token], 98.3KB
    __shared__ float dh[2][16][16];
    __shared__ float dv[2][16][16];
    int win = blockIdx.x;
    int b = win / NWIN_B, wi = win % NWIN_B;
    int wr = wi / NWS, wc = wi % NWS;
    int t = threadIdx.x;
    int tok = t & 255, hf = t >> 8;
    int r = tok >> 4, j = tok & 15;
    int tj1 = (j < 15) ? tok + 1 : tok;
    int tr1 = (r < 15) ? tok + 16 : tok;

    // staging assignment: thread pair (t>>1) owns token stok; t&1 selects 192B half
    int stok = t >> 1;
    size_t srow = xrow(b, wr * WS + (stok >> 4), wc * WS + (stok & 15));

    float sh_ = 0.f, sv_ = 0.f;
    #pragma unroll
    for (int ck = 0; ck < 2; ck++) {
        __syncthreads();   // previous chunk's LDS reads complete before overwrite
        const float4* src = (const float4*)(x + srow + ck * 96) + (t & 1) * 12;
        int cbase = (t & 1) * 48;
        #pragma unroll
        for (int i = 0; i < 12; i++) {
            float4 u = src[i];
            int c = cbase + i * 4;
            xs[c + 0][stok] = u.x; xs[c + 1][stok] = u.y;
            xs[c + 2][stok] = u.z; xs[c + 3][stok] = u.w;
        }
        __syncthreads();
        int c0 = hf * 48;
        #pragma unroll 8
        for (int c = 0; c < 48; c++) {
            float a = xs[c0 + c][tok];
            sh_ += fabsf(xs[c0 + c][tj1] - a);
            sv_ += fabsf(xs[c0 + c][tr1] - a);
        }
    }
    dh[hf][r][j] = (j < 15) ? sh_ : 0.f;
    dv[hf][r][j] = (r < 15) ? sv_ : 0.f;
    __syncthreads();

    float sigma = fabsf(sigp[0]);
    if (t < 16) {
        float acc = 0.f;
        *ctptr(outbuf, win * NN + t * 16) = 0.f;
        for (int jj = 1; jj < 16; jj++) {
            acc += 1.0f + sigma * (dh[0][t][jj - 1] + dh[1][t][jj - 1]);
            *ctptr(outbuf, win * NN + t * 16 + jj) = acc;
        }
    } else if (t < 32) {
        int c = t - 16;
        float acc = 0.f;
        *ctptr(outbuf, CTN + win * NN + c) = 0.f;
        for (int ii = 1; ii < 16; ii++) {
            acc += 1.0f + sigma * (dv[0][ii - 1][c] + dv[1][ii - 1][c]);
            *ctptr(outbuf, CTN + win * NN + ii * 16 + c) = acc;
        }
    }
}

// ------- Kernel B: MFMA windowed attention; f16 att -> first half of own d_out row-slot -------
// 8 waves/block (512 thr); wave w owns q-rows [32w, 32w+32) = window rows 2w, 2w+1.
// SWAPPED QK^T: S^T = mfma(A=K, B=Q); lane owns P[q=dl][k=g*4+r]; PV A-frag via shfl.
// Mask-free fast path for interior windows (wr<11 && wc<11): shift mask identically 0.
// launch_bounds MUST stay (512,4): the cap counts the UNIFIED VGPR+AGPR budget --
// body = ~60 arch + ~24 accum ~= 84, so (512,6)'s cap 85 leaves ~40 arch regs and
// spills catastrophically (r4: 548MB, r7: 444MB scratch writes). PROVEN config:
// (512,4), 60 VGPR, no spill, 2 blocks/CU, ~103us.
__global__ __launch_bounds__(512, 4) void kattn(const float* __restrict__ qkv,
                                                const float* __restrict__ rpb_table,
                                                const float* __restrict__ geo_scale,
                                                float* __restrict__ outbuf) {
    __shared__ __align__(16) uint32_t Klds[256 * 20];     // [token][40 halves], 80B pitch (reused for O)
    __shared__ __align__(16) uint32_t Vt[32 * 140];       // [d][280 halves], 560B pitch (transposed V)
    __shared__ __align__(16) float cth_s[NN];
    __shared__ __align__(16) float ctv_s[NN];
    __shared__ float rpb_s[961];

    int win = blockIdx.x, head = blockIdx.y;
    int b = win / NWIN_B, wi = win % NWIN_B;
    int wr = wi / NWS, wc = wi % NWS;
    int wr16 = wr * WS, wc16 = wc * WS;
    int t = threadIdx.x;
    int dl = t & 15;          // lane&15: A-row / B-col / D-col index
    int g = (t >> 4) & 3;     // lane>>4 within wave: k-chunk / D-row-group
    int g4 = g * 4;
    int w = t >> 6;           // wave id 0..7

    // pre-scaled rpb (fold log2(e) into all additive bias terms)
    for (int i = t; i < 961; i += 512) rpb_s[i] = rpb_table[i * NH + head] * LOG2E;

    // stage K row t -> Klds[t][0..31] (f16, channel order)   [waves 0..3]
    if (t < 256) {
        int r = t >> 4, c = t & 15;
        const float4* k4 = (const float4*)(qkv + qkvrow(b, wr16 + r, wc16 + c) + CC + head * HD);
        uint32_t kp[16];
        #pragma unroll
        for (int c4 = 0; c4 < 8; c4++) {
            float4 u = k4[c4];
            kp[c4 * 2 + 0] = pack_h2(u.x, u.y);
            kp[c4 * 2 + 1] = pack_h2(u.z, u.w);
        }
        uint4* dst = (uint4*)((char*)Klds + t * 80);
        #pragma unroll
        for (int i = 0; i < 4; i++)
            dst[i] = make_uint4(kp[i * 4 + 0], kp[i * 4 + 1], kp[i * 4 + 2], kp[i * 4 + 3]);
    } else if (t < 384) {
        // stage V transposed: Vt[d][k] halves; token pair (2tv, 2tv+1)   [waves 4..5]
        int tv = t - 256;
        int p0 = 2 * tv, p1 = 2 * tv + 1;
        const float4* v0 = (const float4*)(qkv + qkvrow(b, wr16 + (p0 >> 4), wc16 + (p0 & 15)) + 2 * CC + head * HD);
        const float4* v1 = (const float4*)(qkv + qkvrow(b, wr16 + (p1 >> 4), wc16 + (p1 & 15)) + 2 * CC + head * HD);
        #pragma unroll
        for (int c4 = 0; c4 < 8; c4++) {
            float4 a = v0[c4], bu = v1[c4];
            Vt[(c4 * 4 + 0) * 140 + tv] = pack_h2(a.x, bu.x);
            Vt[(c4 * 4 + 1) * 140 + tv] = pack_h2(a.y, bu.y);
            Vt[(c4 * 4 + 2) * 140 + tv] = pack_h2(a.z, bu.z);
            Vt[(c4 * 4 + 3) * 140 + tv] = pack_h2(a.w, bu.w);
        }
    } else {
        // stage ct tables   [waves 6..7]
        int tc = t - 384;   // 0..127
        cth_s[tc]       = *ctptr(outbuf, win * NN + tc);
        cth_s[tc + 128] = *ctptr(outbuf, win * NN + tc + 128);
        ctv_s[tc]       = *ctptr(outbuf, CTN + win * NN + tc);
        ctv_s[tc + 128] = *ctptr(outbuf, CTN + win * NN + tc + 128);
    }
    // Q B-fragments: qt -> window row 2w+qt, col dl; k-dim channels g*8..g*8+7
    f16x8 qf[2];
    #pragma unroll
    for (int qt = 0; qt < 2; qt++) {
        const float* qp = qkv + qkvrow(b, wr16 + 2 * w + qt, wc16 + dl) + head * HD + g * 8;
        float4 u0 = ((const float4*)qp)[0];
        float4 u1 = ((const float4*)qp)[1];
        f16x8 q8;
        q8[0] = (half_t)sat16(u0.x); q8[1] = (half_t)sat16(u0.y);
        q8[2] = (half_t)sat16(u0.z); q8[3] = (half_t)sat16(u0.w);
        q8[4] = (half_t)sat16(u1.x); q8[5] = (half_t)sat16(u1.y);
        q8[6] = (half_t)sat16(u1.z); q8[7] = (half_t)sat16(u1.w);
        qf[qt] = q8;
    }
    __syncthreads();

    // per-lane static bias tables. Element ownership after swap:
    //   lane (g,dl) of tile (qt,kt) holds S[q=(2w+qt)*16+dl][k=kv0+kt*16+g*4+r]
    float gscale2 = geo_scale[head] * LOG2E;
    float ghs[2][4];   // -gscale2*|cth[rq16+ck] - cth[q]|  (static per qt,r)
    f32x4 Dv[2];       // ctv[rq16 + g4 + r]                (static per qt,r)
    int regq[2], qb0[2];
    #pragma unroll
    for (int qt = 0; qt < 2; qt++) {
        int rq = 2 * w + qt;
        float chq = cth_s[rq * 16 + dl];
        f32x4 Bv = *(const f32x4*)&cth_s[rq * 16 + g4];
        Dv[qt] = *(const f32x4*)&ctv_s[rq * 16 + g4];
        #pragma unroll
        for (int r = 0; r < 4; r++) ghs[qt][r] = -gscale2 * fabsf(Bv[r] - chq);
        regq[qt] = 3 * regof(wr16 + rq) + regof(wc16 + dl);
        qb0[qt] = rq * 31 + dl + 480 - g4;
    }
    int regkc[4];
    #pragma unroll
    for (int r = 0; r < 4; r++) regkc[r] = regof(wc16 + g4 + r);
    const float scale2 = 0.17677669529663687f * LOG2E;   // 32^-0.5 * log2(e)

    f32x4 o[2][2];
    #pragma unroll
    for (int qt = 0; qt < 2; qt++) { o[qt][0] = (f32x4){0.f,0.f,0.f,0.f}; o[qt][1] = (f32x4){0.f,0.f,0.f,0.f}; }
    float lq[2] = {0.f, 0.f};

    const char* KB = (const char*)Klds;
    const char* VB = (const char*)Vt;
    const f32x4 zf = {0.f, 0.f, 0.f, 0.f};
    int srcA = ((g & 1) << 5) + dl;   // shfl source lanes for PV A-frag assembly
    int srcB = srcA + 16;
    bool hi = (g >= 2);

#define KVLOOP(MASKED)                                                                  \
    _Pragma("unroll 2")                                                                 \
    for (int kvb = 0; kvb < 8; kvb++) {                                                 \
        int kv0 = kvb * 32;                                                             \
        f16x8 ak0 = *(const f16x8*)(KB + (size_t)(kv0 + dl) * 80 + g * 16);             \
        f16x8 ak1 = *(const f16x8*)(KB + (size_t)(kv0 + 16 + dl) * 80 + g * 16);        \
        f32x4 s[2][2];                                                                  \
        s[0][0] = __builtin_amdgcn_mfma_f32_16x16x32_f16(ak0, qf[0], zf, 0, 0, 0);      \
        s[0][1] = __builtin_amdgcn_mfma_f32_16x16x32_f16(ak1, qf[0], zf, 0, 0, 0);      \
        s[1][0] = __builtin_amdgcn_mfma_f32_16x16x32_f16(ak0, qf[1], zf, 0, 0, 0);      \
        s[1][1] = __builtin_amdgcn_mfma_f32_16x16x32_f16(ak1, qf[1], zf, 0, 0, 0);      \
        f32x4 cv0 = *(const f32x4*)&ctv_s[kv0 + g4];                                    \
        f32x4 cv1 = *(const f32x4*)&ctv_s[kv0 + 16 + g4];                               \
        uint32_t pkk[2][2][2];                                                          \
        _Pragma("unroll")                                                               \
        for (int qt = 0; qt < 2; qt++) {                                                \
            _Pragma("unroll")                                                           \
            for (int kt = 0; kt < 2; kt++) {                                            \
                int rk = kvb * 2 + kt;                                                  \
                int rowreg = MASKED ? 3 * regof(wr16 + rk) : 0;                         \
                int idxk = qb0[qt] - rk * 31;                                           \
                float pr[4];                                                            \
                _Pragma("unroll")                                                       \
                for (int r = 0; r < 4; r++) {                                           \
                    float C = kt ? cv1[r] : cv0[r];                                     \
                    float geoV = fabsf(C - Dv[qt][r]);                                  \
                    float bias = rpb_s[idxk - r] + ghs[qt][r];                          \
                    if (MASKED)                                                         \
                        bias += ((rowreg + regkc[r] == regq[qt]) ? 0.f : -100.f * LOG2E); \
                    float tt2 = fmaf(s[qt][kt][r], scale2, fmaf(-gscale2, geoV, bias)); \
                    tt2 = fminf(fmaxf(tt2, -1000.f), 15.f);                             \
                    float p = EXP2F(tt2);                                               \
                    lq[qt] += p;                                                        \
                    pr[r] = p;                                                          \
                }                                                                       \
                pkk[qt][kt][0] = pack_p(pr[0], pr[1]);                                  \
                pkk[qt][kt][1] = pack_p(pr[2], pr[3]);                                  \
            }                                                                           \
        }                                                                               \
        f16x8 bv0 = *(const f16x8*)(VB + (size_t)dl * 560 + kv0 * 2 + g * 16);          \
        f16x8 bv1 = *(const f16x8*)(VB + (size_t)(16 + dl) * 560 + kv0 * 2 + g * 16);   \
        _Pragma("unroll")                                                               \
        for (int qt = 0; qt < 2; qt++) {                                                \
            uint32_t a00 = __shfl((int)pkk[qt][0][0], srcA), a01 = __shfl((int)pkk[qt][0][1], srcA); \
            uint32_t a10 = __shfl((int)pkk[qt][0][0], srcB), a11 = __shfl((int)pkk[qt][0][1], srcB); \
            uint32_t b00 = __shfl((int)pkk[qt][1][0], srcA), b01 = __shfl((int)pkk[qt][1][1], srcA); \
            uint32_t b10 = __shfl((int)pkk[qt][1][0], srcB), b11 = __shfl((int)pkk[qt][1][1], srcB); \
            u32x4 uu;                                                                   \
            uu.x = hi ? b00 : a00; uu.y = hi ? b01 : a01;                               \
            uu.z = hi ? b10 : a10; uu.w = hi ? b11 : a11;                               \
            f16x8 ap = __builtin_bit_cast(f16x8, uu);                                   \
            o[qt][0] = __builtin_amdgcn_mfma_f32_16x16x32_f16(ap, bv0, o[qt][0], 0, 0, 0); \
            o[qt][1] = __builtin_amdgcn_mfma_f32_16x16x32_f16(ap, bv1, o[qt][1], 0, 0, 0); \
        }                                                                               \
    }

    if (wr < 11 && wc < 11) {
        // interior window: all region ids 0 -> shift mask identically zero
        KVLOOP(false)
    } else {
        KVLOOP(true)
    }
#undef KVLOOP

    // row sums: lane holds partial sum for q=dl of each qt tile; reduce over the
    // 4 g-groups (lanes ^16, ^32), then fetch inv for the o-rows this lane owns.
    float invr[2][4];
    #pragma unroll
    for (int qt = 0; qt < 2; qt++) {
        float li = lq[qt];
        li += __shfl_xor(li, 16);
        li += __shfl_xor(li, 32);
        float iv = 1.0f / li;
        #pragma unroll
        for (int r = 0; r < 4; r++) invr[qt][r] = __shfl(iv, g4 + r);
    }

    // all waves done reading K -> reuse Klds as per-wave O transpose buffer
    __syncthreads();
    char* OB = (char*)Klds + w * 2560;   // [32 rows][80B]
    #pragma unroll
    for (int qt = 0; qt < 2; qt++)
        #pragma unroll
        for (int dt = 0; dt < 2; dt++)
            #pragma unroll
            for (int r = 0; r < 4; r++) {
                float val = o[qt][dt][r] * invr[qt][r];
                *(half_t*)(OB + (qt * 16 + g4 + r) * 80 + (dt * 16 + dl) * 2) = (half_t)sat16(val);
            }

    // wave w stores its own 32 tokens; lane pair (lp, half) -> 32B each (no barrier needed)
    int lane = t & 63;
    int lp = lane >> 1, half = lane & 1;
    int tok = 32 * w + lp;
    int rr = tok >> 4, pc = tok & 15;
    int oh = wr16 + rr + SHIFTS; if (oh >= HH) oh -= HH;
    int ow = wc16 + pc + SHIFTS; if (ow >= WWW) ow -= WWW;
    size_t R = (size_t)b * (HH * WWW) + (size_t)oh * WWW + ow;
    uint4* o4p = (uint4*)outbuf;
    const uint4* src = (const uint4*)(OB + lp * 80 + half * 32);
    size_t base4 = R * 48 + head * 4 + half * 2;
    o4p[base4 + 0] = src[0];
    o4p[base4 + 1] = src[1];
}

// ------- Kernel C: MFMA projection GEMM on d_out (f16 A in slot-half, f32 out full slot) -------
// 512 threads = 8 waves; wave w owns rows [R0+16w, R0+16w+16) -> reads its own rows' f16
// halves (A-frags direct from global, L3-resident) and stores f32 to the same rows:
// stores depend on acc -> all A loads retired first; cross-wave rows disjoint -> race-free.
// W staged once per block as f16 in LDS (400B pitch -> 2-way-free b128 B-frags).
__global__ __launch_bounds__(512, 4) void kproj(float* __restrict__ data,
                                                const float* __restrict__ proj_w,
                                                const float* __restrict__ proj_b) {
    __shared__ __align__(16) uint32_t Wh[192 * 100];   // f16 W[j][c], pitch 400B (192 ch + pad)
    int t = threadIdx.x;
    size_t R0 = (size_t)blockIdx.x * 128;

    // stage W -> f16 LDS: W[j][c] row-major, halves contiguous in c
    const float4* pw4 = (const float4*)proj_w;
    for (int q = t; q < 9216; q += 512) {
        int j = q / 48, c4 = q - j * 48;
        float4 u = pw4[q];
        *(uint2*)&Wh[j * 100 + c4 * 2] = make_uint2(pack_h2(u.x, u.y), pack_h2(u.z, u.w));
    }
    __syncthreads();

    int dl = t & 15, g = (t >> 4) & 3, w = t >> 6;
    const char* WB = (const char*)Wh;
    const char* AB = (const char*)data;

    f32x4 acc[12];
    #pragma unroll
    for (int i = 0; i < 12; i++) acc[i] = (f32x4){0.f, 0.f, 0.f, 0.f};

    // A-frag: row = dl (global row R0+16w+dl), k = c = ch*32 + g*8 + j  (16B load per chunk)
    size_t arow = (size_t)(R0 + w * 16 + dl) * 768;
    #pragma unroll
    for (int ch = 0; ch < 6; ch++) {
        f16x8 af = *(const f16x8*)(AB + arow + ch * 64 + g * 16);
        #pragma unroll
        for (int jt = 0; jt < 12; jt++) {
            // B-frag: col = j = jt*16+dl, k = c  (Wh[j][c] contiguous halves)
            f16x8 bf = *(const f16x8*)(WB + (size_t)(jt * 16 + dl) * 400 + ch * 64 + g * 16);
            acc[jt] = __builtin_amdgcn_mfma_f32_16x16x32_f16(af, bf, acc[jt], 0, 0, 0);
        }
    }

    // bias + f32 stores: D row = g*4+r (own wave's rows), col = jt*16+dl
    float bvv[12];
    #pragma unroll
    for (int jt = 0; jt < 12; jt++) bvv[jt] = proj_b[jt * 16 + dl];
    size_t orow = (size_t)(R0 + w * 16 + g * 4) * 192;
    #pragma unroll
    for (int jt = 0; jt < 12; jt++)
        #pragma unroll
        for (int r = 0; r < 4; r++)
            data[orow + (size_t)r * 192 + jt * 16 + dl] = acc[jt][r] + bvv[jt];
}

extern "C" void kernel_launch(void* const* d_in, const int* in_sizes, int n_in,
                              void* d_out, int out_size, void* d_ws, size_t ws_size,
                              hipStream_t stream) {
    // Resolve float32 inputs by unique element count (belt-and-braces vs dict order)
    const float *x = nullptr, *qkv = nullptr, *rpb = nullptr, *gsc = nullptr,
                *pw = nullptr, *pb = nullptr, *sig = nullptr;
    for (int i = 0; i < n_in; i++) {
        switch (in_sizes[i]) {
            case 14155776: x   = (const float*)d_in[i]; break;  // 2*192*192*192
            case 42467328: qkv = (const float*)d_in[i]; break;  // 3x
            case 5766:     rpb = (const float*)d_in[i]; break;  // 961*6
            case 6:        gsc = (const float*)d_in[i]; break;  // NH
            case 36864:    pw  = (const float*)d_in[i]; break;  // 192*192
            case 192:      pb  = (const float*)d_in[i]; break;
            default: break;  // rpi(65536), attn_mask(589824), scalars
        }
    }
    // geo_sigma: first size-1 input in dict order (index 4 per setup_inputs)
    if (n_in > 4 && in_sizes[4] == 1) sig = (const float*)d_in[4];
    else for (int i = 0; i < n_in; i++) if (in_sizes[i] == 1) { sig = (const float*)d_in[i]; break; }
    // fallback to dict order if anything unresolved
    if (!x)   x   = (const float*)d_in[0];
    if (!qkv) qkv = (const float*)d_in[1];
    if (!rpb) rpb = (const float*)d_in[2];
    if (!gsc) gsc = (const float*)d_in[3];
    if (!sig) sig = (const float*)d_in[4];
    if (!pw)  pw  = (const float*)d_in[5];
    if (!pb)  pb  = (const float*)d_in[6];

    float* out = (float*)d_out;   // reference output dtype: float32
    // d_ws unused: ct tables live in second halves of d_out row-slots 0..3071;
    // f16 att lives in the first half of each row's own f32 slot (in-place kproj).

    kgeo<<<dim3(NWIN), dim3(512), 0, stream>>>(x, sig, out);
    kattn<<<dim3(NWIN, NH), dim3(512), 0, stream>>>(qkv, rpb, gsc, out);
    kproj<<<dim3((NWIN * NN) / 128), dim3(512), 0, stream>>>(out, pw, pb);
}

// Round 9
// 375.575 us; speedup vs baseline: 1.4879x; 1.0538x over previous
//
#include <hip/hip_runtime.h>
#include <stdint.h>

// Problem constants (B,H,W,C)=(2,192,192,192), WS=16, SHIFT=8, NH=6
#define HH 192
#define WWW 192
#define CC 192
#define WS 16
#define SHIFTS 8
#define NH 6
#define HD 32
#define NN 256
#define NWS 12
#define NWIN_B 144
#define NWIN 288
#define CTN (NWIN * NN)          // 73728 floats per ct table

typedef _Float16 half_t;
typedef half_t half2_t __attribute__((ext_vector_type(2)));
typedef half_t f16x8 __attribute__((ext_vector_type(8)));   // MFMA A/B frag (4 VGPR)
typedef float f32x4 __attribute__((ext_vector_type(4)));    // MFMA C/D frag
typedef uint32_t u32x4 __attribute__((ext_vector_type(4)));

#define LOG2E 1.4426950408889634f

#if __has_builtin(__builtin_amdgcn_exp2f)
#define EXP2F(x) __builtin_amdgcn_exp2f(x)
#else
#define EXP2F(x) __expf(0.6931471805599453f * (x))
#endif

// saturating f32->f16 pack: launders NaN (fminf/fmaxf drop NaN operand) and caps inf
__device__ __forceinline__ float sat16(float a) {
    return fminf(fmaxf(a, -60000.f), 60000.f);
}
__device__ __forceinline__ uint32_t pack_h2(float a, float b) {
    half2_t h; h.x = (half_t)sat16(a); h.y = (half_t)sat16(b);
    return __builtin_bit_cast(uint32_t, h);
}
// p is already bounded in [0, 2^15] (exp2 of clamped arg): plain rte casts
__device__ __forceinline__ uint32_t pack_p(float a, float b) {
    half2_t h; h.x = (half_t)a; h.y = (half_t)b;
    return __builtin_bit_cast(uint32_t, h);
}

// post-shift (sh,sw) -> original coords (roll by -SHIFT: s[i] = x[(i+SHIFT)%N])
__device__ __forceinline__ size_t xrow(int b, int sh, int sw) {
    int oh = sh + SHIFTS; if (oh >= HH) oh -= HH;
    int ow = sw + SHIFTS; if (ow >= WWW) ow -= WWW;
    return ((size_t)((b * HH + oh) * WWW + ow)) * CC;
}
__device__ __forceinline__ size_t qkvrow(int b, int sh, int sw) {
    int oh = sh + SHIFTS; if (oh >= HH) oh -= HH;
    int ow = sw + SHIFTS; if (ow >= WWW) ow -= WWW;
    return ((size_t)((b * HH + oh) * WWW + ow)) * (3 * CC);
}
// shift-mask region id along one axis (post-shift / mask-image coordinates)
__device__ __forceinline__ int regof(int v) { return v < (HH - WS) ? 0 : (v < (HH - SHIFTS) ? 1 : 2); }

// ct tables parked in SECOND halves (floats [96,192)) of d_out row-slots 0..3071.
// flat index q in [0, 2*CTN) -> float position in d_out.
__device__ __forceinline__ float* ctptr(float* o, int q) {
    int slot = q / 96;            // magic-mul, constant divisor
    int off = q - slot * 96;
    return o + (size_t)slot * CC + 96 + off;
}

// ---------------- Kernel A: geo cumsum tables (once per window) ----------------
// 512 threads. Window x staged into LDS TRANSPOSED xs[ch][token] in two 96-channel
// chunks: global bytes read exactly once, fully coalesced.
__global__ __launch_bounds__(512) void kgeo(const float* __restrict__ x,
                                            const float* __restrict__ sigp,
                                            float* __restrict__ outbuf) {
    __shared__ float xs[96][256];     // [channel-in-chunk][token], 98.3KB
    __shared__ float dh[2][16][16];
    __shared__ float dv[2][16][16];
    int win = blockIdx.x;
    int b = win / NWIN_B, wi = win % NWIN_B;
    int wr = wi / NWS, wc = wi % NWS;
    int t = threadIdx.x;
    int tok = t & 255, hf = t >> 8;
    int r = tok >> 4, j = tok & 15;
    int tj1 = (j < 15) ? tok + 1 : tok;
    int tr1 = (r < 15) ? tok + 16 : tok;

    int stok = t >> 1;
    size_t srow = xrow(b, wr * WS + (stok >> 4), wc * WS + (stok & 15));

    float sh_ = 0.f, sv_ = 0.f;
    #pragma unroll
    for (int ck = 0; ck < 2; ck++) {
        __syncthreads();   // previous chunk's LDS reads complete before overwrite
        const float4* src = (const float4*)(x + srow + ck * 96) + (t & 1) * 12;
        int cbase = (t & 1) * 48;
        #pragma unroll
        for (int i = 0; i < 12; i++) {
            float4 u = src[i];
            int c = cbase + i * 4;
            xs[c + 0][stok] = u.x; xs[c + 1][stok] = u.y;
            xs[c + 2][stok] = u.z; xs[c + 3][stok] = u.w;
        }
        __syncthreads();
        int c0 = hf * 48;
        #pragma unroll 8
        for (int c = 0; c < 48; c++) {
            float a = xs[c0 + c][tok];
            sh_ += fabsf(xs[c0 + c][tj1] - a);
            sv_ += fabsf(xs[c0 + c][tr1] - a);
        }
    }
    dh[hf][r][j] = (j < 15) ? sh_ : 0.f;
    dv[hf][r][j] = (r < 15) ? sv_ : 0.f;
    __syncthreads();

    float sigma = fabsf(sigp[0]);
    if (t < 16) {
        float acc = 0.f;
        *ctptr(outbuf, win * NN + t * 16) = 0.f;
        for (int jj = 1; jj < 16; jj++) {
            acc += 1.0f + sigma * (dh[0][t][jj - 1] + dh[1][t][jj - 1]);
            *ctptr(outbuf, win * NN + t * 16 + jj) = acc;
        }
    } else if (t < 32) {
        int c = t - 16;
        float acc = 0.f;
        *ctptr(outbuf, CTN + win * NN + c) = 0.f;
        for (int ii = 1; ii < 16; ii++) {
            acc += 1.0f + sigma * (dv[0][ii - 1][c] + dv[1][ii - 1][c]);
            *ctptr(outbuf, CTN + win * NN + ii * 16 + c) = acc;
        }
    }
}

// ------- Kernel B: MFMA windowed attention; f16 att -> first half of own d_out row-slot -------
// 8 waves/block (512 thr); wave w owns q-rows [32w, 32w+32) = window rows 2w, 2w+1.
// SWAPPED QK^T with PERMUTED K A-frag: A-row dl loads token pi_kt(dl) =
// 8*(dl>>2)+(dl&3)+4kt, so lane (g,dl) of tile kt ends up owning
// P[q=dl][tok = kv0+8g+4kt+r] -- exactly its own PV A-fragment. The PV A-frag is a
// pure register concatenation: ZERO cross-lane ops (r8 had 16 ds_bpermute+8 selects
// per iter -- the DS pipe was the serialized bottleneck: ~260cy/wave/iter).
// rpb staged as swizzled b128 table rpbT[u][m12][r] = rpb[u*31+m12+3-r] (13.9KB):
// 4 b128 reads/iter replace 16 scalar gathers. DS/iter: 260cy -> ~120cy.
// launch_bounds MUST stay (512,4): cap counts unified VGPR+AGPR; cap 85 spilled
// catastrophically (r4/r7: 444-548MB scratch). LDS 54.3KB -> 2 blocks/CU.
__global__ __launch_bounds__(512, 4) void kattn(const float* __restrict__ qkv,
                                                const float* __restrict__ rpb_table,
                                                const float* __restrict__ geo_scale,
                                                float* __restrict__ outbuf) {
    __shared__ __align__(16) uint32_t Klds[256 * 20];     // [token][40 halves], 80B pitch (reused for O)
    __shared__ __align__(16) uint32_t Vt[32 * 140];       // [d][280 halves], 560B pitch (transposed V)
    __shared__ __align__(16) float cth_s[NN];
    __shared__ __align__(16) float ctv_s[NN];
    __shared__ __align__(16) float rpbT[868 * 4];         // [u15*28 + m12][r], 13.9KB

    int win = blockIdx.x, head = blockIdx.y;
    int b = win / NWIN_B, wi = win % NWIN_B;
    int wr = wi / NWS, wc = wi % NWS;
    int wr16 = wr * WS, wc16 = wc * WS;
    int t = threadIdx.x;
    int dl = t & 15;          // lane&15: A-row / B-col / D-col index
    int g = (t >> 4) & 3;     // lane>>4 within wave: k-chunk / D-row-group
    int w = t >> 6;           // wave id 0..7

    // build swizzled rpb table: rpbT[u*28+m12][r] = rpb[u*31 + m12 + 3 - r] * LOG2E
    // (u = rq-rk+15 in [0,30]; m12 = dl-8(g&1)-4kt+12 in [0,27]; verified in-bounds)
    for (int e = t; e < 868; e += 512) {
        int u = e / 28, m12 = e - u * 28;
        int base = u * 31 + m12 + 3;        // flat rpi index for r=0; in [3,960]
        float4 v;
        v.x = rpb_table[(base    ) * NH + head] * LOG2E;
        v.y = rpb_table[(base - 1) * NH + head] * LOG2E;
        v.z = rpb_table[(base - 2) * NH + head] * LOG2E;
        v.w = rpb_table[(base - 3) * NH + head] * LOG2E;
        *(float4*)&rpbT[e * 4] = v;
    }

    // stage K row t -> Klds[t][0..31] (f16, channel order)   [waves 0..3]
    if (t < 256) {
        int r = t >> 4, c = t & 15;
        const float4* k4 = (const float4*)(qkv + qkvrow(b, wr16 + r, wc16 + c) + CC + head * HD);
        uint32_t kp[16];
        #pragma unroll
        for (int c4 = 0; c4 < 8; c4++) {
            float4 u = k4[c4];
            kp[c4 * 2 + 0] = pack_h2(u.x, u.y);
            kp[c4 * 2 + 1] = pack_h2(u.z, u.w);
        }
        uint4* dst = (uint4*)((char*)Klds + t * 80);
        #pragma unroll
        for (int i = 0; i < 4; i++)
            dst[i] = make_uint4(kp[i * 4 + 0], kp[i * 4 + 1], kp[i * 4 + 2], kp[i * 4 + 3]);
    } else if (t < 384) {
        // stage V transposed: Vt[d][k] halves; token pair (2tv, 2tv+1)   [waves 4..5]
        int tv = t - 256;
        int p0 = 2 * tv, p1 = 2 * tv + 1;
        const float4* v0 = (const float4*)(qkv + qkvrow(b, wr16 + (p0 >> 4), wc16 + (p0 & 15)) + 2 * CC + head * HD);
        const float4* v1 = (const float4*)(qkv + qkvrow(b, wr16 + (p1 >> 4), wc16 + (p1 & 15)) + 2 * CC + head * HD);
        #pragma unroll
        for (int c4 = 0; c4 < 8; c4++) {
            float4 a = v0[c4], bu = v1[c4];
            Vt[(c4 * 4 + 0) * 140 + tv] = pack_h2(a.x, bu.x);
            Vt[(c4 * 4 + 1) * 140 + tv] = pack_h2(a.y, bu.y);
            Vt[(c4 * 4 + 2) * 140 + tv] = pack_h2(a.z, bu.z);
            Vt[(c4 * 4 + 3) * 140 + tv] = pack_h2(a.w, bu.w);
        }
    } else {
        // stage ct tables   [waves 6..7]
        int tc = t - 384;   // 0..127
        cth_s[tc]       = *ctptr(outbuf, win * NN + tc);
        cth_s[tc + 128] = *ctptr(outbuf, win * NN + tc + 128);
        ctv_s[tc]       = *ctptr(outbuf, CTN + win * NN + tc);
        ctv_s[tc + 128] = *ctptr(outbuf, CTN + win * NN + tc + 128);
    }
    // Q B-fragments: qt -> window row 2w+qt, col dl; k-dim channels g*8..g*8+7
    f16x8 qf[2];
    #pragma unroll
    for (int qt = 0; qt < 2; qt++) {
        const float* qp = qkv + qkvrow(b, wr16 + 2 * w + qt, wc16 + dl) + head * HD + g * 8;
        float4 u0 = ((const float4*)qp)[0];
        float4 u1 = ((const float4*)qp)[1];
        f16x8 q8;
        q8[0] = (half_t)sat16(u0.x); q8[1] = (half_t)sat16(u0.y);
        q8[2] = (half_t)sat16(u0.z); q8[3] = (half_t)sat16(u0.w);
        q8[4] = (half_t)sat16(u1.x); q8[5] = (half_t)sat16(u1.y);
        q8[6] = (half_t)sat16(u1.z); q8[7] = (half_t)sat16(u1.w);
        qf[qt] = q8;
    }
    __syncthreads();

    // Element ownership (permuted): lane (g,dl) of tile (qt,kt) reg r holds
    //   S[q=(2w+qt)*16+dl][tok = kv0 + 8g + 4kt + r]
    //   -> rk = 2kvb + (g>>1), ck = 8(g&1) + 4kt + r
    int g1_8 = 8 * (g & 1);
    float gscale2 = geo_scale[head] * LOG2E;
    f32x4 ghs[2][2];   // -gscale2*|cth[rq16+ck] - cth[q]|  (static per qt,kt,r)
    f32x4 Dv[2][2];    // ctv[rq16 + ck]                    (static per qt,kt,r)
    int regq[2], bidx[2][2];
    #pragma unroll
    for (int qt = 0; qt < 2; qt++) {
        int rq = 2 * w + qt;
        float chq = cth_s[rq * 16 + dl];
        #pragma unroll
        for (int kt = 0; kt < 2; kt++) {
            f32x4 Bv = *(const f32x4*)&cth_s[rq * 16 + g1_8 + 4 * kt];
            Dv[qt][kt] = *(const f32x4*)&ctv_s[rq * 16 + g1_8 + 4 * kt];
            f32x4 gh;
            #pragma unroll
            for (int r = 0; r < 4; r++) gh[r] = -gscale2 * fabsf(Bv[r] - chq);
            ghs[qt][kt] = gh;
            // rpbT slot base: u = (2w+qt) - (g>>1) + 15 - 2kvb ; m12 = dl - g1_8 + 12 - 4kt
            bidx[qt][kt] = (2 * w + qt - (g >> 1) + 15) * 28 + (dl - g1_8 + 12 - 4 * kt);
        }
        regq[qt] = 3 * regof(wr16 + rq) + regof(wc16 + dl);
    }
    int wk8 = wc16 + g1_8;   // mask col base (masked path only)
    const float scale2 = 0.17677669529663687f * LOG2E;   // 32^-0.5 * log2(e)

    f32x4 o[2][2];
    #pragma unroll
    for (int qt = 0; qt < 2; qt++) { o[qt][0] = (f32x4){0.f,0.f,0.f,0.f}; o[qt][1] = (f32x4){0.f,0.f,0.f,0.f}; }
    float lq[2] = {0.f, 0.f};

    const char* KB = (const char*)Klds;
    const char* VB = (const char*)Vt;
    const f32x4 zf = {0.f, 0.f, 0.f, 0.f};
    int tA = 8 * (dl >> 2) + (dl & 3);   // permuted A-row token (kt=0); kt=1 adds 4

#define KVLOOP(MASKED)                                                                  \
    _Pragma("unroll 2")                                                                 \
    for (int kvb = 0; kvb < 8; kvb++) {                                                 \
        int kv0 = kvb * 32;                                                             \
        f16x8 ak0 = *(const f16x8*)(KB + (size_t)(kv0 + tA) * 80 + g * 16);             \
        f16x8 ak1 = *(const f16x8*)(KB + (size_t)(kv0 + tA + 4) * 80 + g * 16);         \
        f32x4 s[2][2];                                                                  \
        s[0][0] = __builtin_amdgcn_mfma_f32_16x16x32_f16(ak0, qf[0], zf, 0, 0, 0);      \
        s[0][1] = __builtin_amdgcn_mfma_f32_16x16x32_f16(ak1, qf[0], zf, 0, 0, 0);      \
        s[1][0] = __builtin_amdgcn_mfma_f32_16x16x32_f16(ak0, qf[1], zf, 0, 0, 0);      \
        s[1][1] = __builtin_amdgcn_mfma_f32_16x16x32_f16(ak1, qf[1], zf, 0, 0, 0);      \
        f32x4 cv0 = *(const f32x4*)&ctv_s[kv0 + 8 * g];                                 \
        f32x4 cv1 = *(const f32x4*)&ctv_s[kv0 + 8 * g + 4];                             \
        int rowreg = MASKED ? 3 * regof(wr16 + 2 * kvb + (g >> 1)) : 0;                 \
        uint32_t pkk[2][2][2];                                                          \
        _Pragma("unroll")                                                               \
        for (int qt = 0; qt < 2; qt++) {                                                \
            _Pragma("unroll")                                                           \
            for (int kt = 0; kt < 2; kt++) {                                            \
                f32x4 rv = *(const f32x4*)&rpbT[(bidx[qt][kt] - 56 * kvb) * 4];         \
                float pr[4];                                                            \
                _Pragma("unroll")                                                       \
                for (int r = 0; r < 4; r++) {                                           \
                    float C = kt ? cv1[r] : cv0[r];                                     \
                    float geoV = fabsf(C - Dv[qt][kt][r]);                              \
                    float bias = rv[r] + ghs[qt][kt][r];                                \
                    if (MASKED)                                                         \
                        bias += ((rowreg + regof(wk8 + 4 * kt + r) == regq[qt]) ? 0.f : -100.f * LOG2E); \
                    float tt2 = fmaf(s[qt][kt][r], scale2, fmaf(-gscale2, geoV, bias)); \
                    tt2 = fminf(fmaxf(tt2, -1000.f), 15.f);                             \
                    float p = EXP2F(tt2);                                               \
                    lq[qt] += p;                                                        \
                    pr[r] = p;                                                          \
                }                                                                       \
                pkk[qt][kt][0] = pack_p(pr[0], pr[1]);                                  \
                pkk[qt][kt][1] = pack_p(pr[2], pr[3]);                                  \
            }                                                                           \
        }                                                                               \
        f16x8 bv0 = *(const f16x8*)(VB + (size_t)dl * 560 + kv0 * 2 + g * 16);          \
        f16x8 bv1 = *(const f16x8*)(VB + (size_t)(16 + dl) * 560 + kv0 * 2 + g * 16);   \
        _Pragma("unroll")                                                               \
        for (int qt = 0; qt < 2; qt++) {                                                \
            u32x4 uu;                                                                   \
            uu.x = pkk[qt][0][0]; uu.y = pkk[qt][0][1];                                 \
            uu.z = pkk[qt][1][0]; uu.w = pkk[qt][1][1];                                 \
            f16x8 ap = __builtin_bit_cast(f16x8, uu);                                   \
            o[qt][0] = __builtin_amdgcn_mfma_f32_16x16x32_f16(ap, bv0, o[qt][0], 0, 0, 0); \
            o[qt][1] = __builtin_amdgcn_mfma_f32_16x16x32_f16(ap, bv1, o[qt][1], 0, 0, 0); \
        }                                                                               \
    }

    if (wr < 11 && wc < 11) {
        // interior window: all region ids 0 -> shift mask identically zero
        KVLOOP(false)
    } else {
        KVLOOP(true)
    }
#undef KVLOOP

    // row sums: lane holds partial sum for q=dl of each qt tile; reduce over the
    // 4 g-groups (lanes ^16, ^32), then fetch inv for the o-rows this lane owns.
    float invr[2][4];
    #pragma unroll
    for (int qt = 0; qt < 2; qt++) {
        float li = lq[qt];
        li += __shfl_xor(li, 16);
        li += __shfl_xor(li, 32);
        float iv = 1.0f / li;
        #pragma unroll
        for (int r = 0; r < 4; r++) invr[qt][r] = __shfl(iv, g * 4 + r);
    }

    // all waves done reading K -> reuse Klds as per-wave O transpose buffer
    __syncthreads();
    char* OB = (char*)Klds + w * 2560;   // [32 rows][80B]
    #pragma unroll
    for (int qt = 0; qt < 2; qt++)
        #pragma unroll
        for (int dt = 0; dt < 2; dt++)
            #pragma unroll
            for (int r = 0; r < 4; r++) {
                float val = o[qt][dt][r] * invr[qt][r];
                *(half_t*)(OB + (qt * 16 + g * 4 + r) * 80 + (dt * 16 + dl) * 2) = (half_t)sat16(val);
            }

    // wave w stores its own 32 tokens; lane pair (lp, half) -> 32B each (no barrier needed)
    int lane = t & 63;
    int lp = lane >> 1, half = lane & 1;
    int tok = 32 * w + lp;
    int rr = tok >> 4, pc = tok & 15;
    int oh = wr16 + rr + SHIFTS; if (oh >= HH) oh -= HH;
    int ow = wc16 + pc + SHIFTS; if (ow >= WWW) ow -= WWW;
    size_t R = (size_t)b * (HH * WWW) + (size_t)oh * WWW + ow;
    uint4* o4p = (uint4*)outbuf;
    const uint4* src = (const uint4*)(OB + lp * 80 + half * 32);
    size_t base4 = R * 48 + head * 4 + half * 2;
    o4p[base4 + 0] = src[0];
    o4p[base4 + 1] = src[1];
}

// ------- Kernel C: MFMA projection GEMM on d_out (f16 A in slot-half, f32 out full slot) -------
// 512 threads = 8 waves; wave w owns rows [R0+16w, R0+16w+16) -> reads its own rows' f16
// halves (A-frags direct from global, L3-resident) and stores f32 to the same rows:
// stores depend on acc -> all A loads retired first; cross-wave rows disjoint -> race-free.
// W staged once per block as f16 in LDS (400B pitch -> 2-way-free b128 B-frags).
__global__ __launch_bounds__(512, 4) void kproj(float* __restrict__ data,
                                                const float* __restrict__ proj_w,
                                                const float* __restrict__ proj_b) {
    __shared__ __align__(16) uint32_t Wh[192 * 100];   // f16 W[j][c], pitch 400B (192 ch + pad)
    int t = threadIdx.x;
    size_t R0 = (size_t)blockIdx.x * 128;

    // stage W -> f16 LDS: W[j][c] row-major, halves contiguous in c
    const float4* pw4 = (const float4*)proj_w;
    for (int q = t; q < 9216; q += 512) {
        int j = q / 48, c4 = q - j * 48;
        float4 u = pw4[q];
        *(uint2*)&Wh[j * 100 + c4 * 2] = make_uint2(pack_h2(u.x, u.y), pack_h2(u.z, u.w));
    }
    __syncthreads();

    int dl = t & 15, g = (t >> 4) & 3, w = t >> 6;
    const char* WB = (const char*)Wh;
    const char* AB = (const char*)data;

    f32x4 acc[12];
    #pragma unroll
    for (int i = 0; i < 12; i++) acc[i] = (f32x4){0.f, 0.f, 0.f, 0.f};

    // A-frag: row = dl (global row R0+16w+dl), k = c = ch*32 + g*8 + j  (16B load per chunk)
    size_t arow = (size_t)(R0 + w * 16 + dl) * 768;
    #pragma unroll
    for (int ch = 0; ch < 6; ch++) {
        f16x8 af = *(const f16x8*)(AB + arow + ch * 64 + g * 16);
        #pragma unroll
        for (int jt = 0; jt < 12; jt++) {
            // B-frag: col = j = jt*16+dl, k = c  (Wh[j][c] contiguous halves)
            f16x8 bf = *(const f16x8*)(WB + (size_t)(jt * 16 + dl) * 400 + ch * 64 + g * 16);
            acc[jt] = __builtin_amdgcn_mfma_f32_16x16x32_f16(af, bf, acc[jt], 0, 0, 0);
        }
    }

    // bias + f32 stores: D row = g*4+r (own wave's rows), col = jt*16+dl
    float bvv[12];
    #pragma unroll
    for (int jt = 0; jt < 12; jt++) bvv[jt] = proj_b[jt * 16 + dl];
    size_t orow = (size_t)(R0 + w * 16 + g * 4) * 192;
    #pragma unroll
    for (int jt = 0; jt < 12; jt++)
        #pragma unroll
        for (int r = 0; r < 4; r++)
            data[orow + (size_t)r * 192 + jt * 16 + dl] = acc[jt][r] + bvv[jt];
}

extern "C" void kernel_launch(void* const* d_in, const int* in_sizes, int n_in,
                              void* d_out, int out_size, void* d_ws, size_t ws_size,
                              hipStream_t stream) {
    // Resolve float32 inputs by unique element count (belt-and-braces vs dict order)
    const float *x = nullptr, *qkv = nullptr, *rpb = nullptr, *gsc = nullptr,
                *pw = nullptr, *pb = nullptr, *sig = nullptr;
    for (int i = 0; i < n_in; i++) {
        switch (in_sizes[i]) {
            case 14155776: x   = (const float*)d_in[i]; break;  // 2*192*192*192
            case 42467328: qkv = (const float*)d_in[i]; break;  // 3x
            case 5766:     rpb = (const float*)d_in[i]; break;  // 961*6
            case 6:        gsc = (const float*)d_in[i]; break;  // NH
            case 36864:    pw  = (const float*)d_in[i]; break;  // 192*192
            case 192:      pb  = (const float*)d_in[i]; break;
            default: break;  // rpi(65536), attn_mask(589824), scalars
        }
    }
    // geo_sigma: first size-1 input in dict order (index 4 per setup_inputs)
    if (n_in > 4 && in_sizes[4] == 1) sig = (const float*)d_in[4];
    else for (int i = 0; i < n_in; i++) if (in_sizes[i] == 1) { sig = (const float*)d_in[i]; break; }
    // fallback to dict order if anything unresolved
    if (!x)   x   = (const float*)d_in[0];
    if (!qkv) qkv = (const float*)d_in[1];
    if (!rpb) rpb = (const float*)d_in[2];
    if (!gsc) gsc = (const float*)d_in[3];
    if (!sig) sig = (const float*)d_in[4];
    if (!pw)  pw  = (const float*)d_in[5];
    if (!pb)  pb  = (const float*)d_in[6];

    float* out = (float*)d_out;   // reference output dtype: float32
    // d_ws unused: ct tables live in second halves of d_out row-slots 0..3071;
    // f16 att lives in the first half of each row's own f32 slot (in-place kproj).

    kgeo<<<dim3(NWIN), dim3(512), 0, stream>>>(x, sig, out);
    kattn<<<dim3(NWIN, NH), dim3(512), 0, stream>>>(qkv, rpb, gsc, out);
    kproj<<<dim3((NWIN * NN) / 128), dim3(512), 0, stream>>>(out, pw, pb);
}